// Round 1
// 220.856 us; speedup vs baseline: 1.1039x; 1.1039x over previous
//
#include <hip/hip_runtime.h>
#include <stddef.h>

// Correlation cost volume via bf16 MFMA band-matmul.
// out[b, di*9+dj, h, w] = (1/256) * sum_c x1[b,c,h,w] * x2[b,c,h+di-4,w+dj-4]
// B=4, C=256, H=96, W=192.
//
// R3 -> R4: R3 was occupancy-bound: acc[9][2] (72 AGPRs, unified file) + 84
// VGPRs ~= 160 regs/wave -> 3 waves/SIMD budget -> only ONE 8-wave block per
// CU (Occupancy 18.6%), so every vmcnt/barrier wait was dead CU time (HBM at
// 2.77 of 6.3 TB/s). Fixes:
//  1) __launch_bounds__(512,4): force <=128 regs -> 2 blocks/CU. Enabled by
//     hoisting all addressing to 32-bit offsets bumped per chunk (no per-chunk
//     64-bit mul chains).
//  2) task remap (seg fastest, cp mid, row slow): LDS write banks go from ~8
//     (8-way conflict, 2.07e7 conflict cycles) to ~22 over the wave (~3-way).
//  3) XCD-aware tile swizzle: 72 consecutive tiles per XCD -> halo re-reads
//     hit the XCD's L2 (per-chunk slab ~1.4 MB < 4 MB).
//  4) next-chunk x2 loads issued before the mid-chunk barrier.

#define NB 4
#define NC 256
#define HH 96
#define WW 192
#define TW 16
#define TH 8
#define KC 32
#define NROWS 16   // TH + 8 halo rows
#define CHW (HH * WW)         // 18432 floats per channel plane
#define KSTRIDE (KC * CHW)    // chunk-to-chunk float offset

// Flat LDS bf16 layout for x2 tile: [row][kg=k/8][n][k%8] (k-innermost 8 ->
// one bf16x8 B-frag = 1 ds_read_b128). KS=264, RS=1096 stagger bank groups.
#define KS 264
#define RS 1096
#define XBI(row, kg, n) ((row) * RS + (kg) * KS + (n) * 8)

typedef __attribute__((ext_vector_type(8))) short bf16x8;
typedef __attribute__((ext_vector_type(4))) float f32x4;

__device__ __forceinline__ unsigned short f2bf(float f) {
    union { float f; unsigned u; } c; c.f = f;
    unsigned r = c.u + 0x7FFFu + ((c.u >> 16) & 1u);   // round-to-nearest-even
    return (unsigned short)(r >> 16);
}

__global__ __launch_bounds__(512, 4) void corr_mfma(
    const float* __restrict__ x1, const float* __restrict__ x2,
    float* __restrict__ out)
{
    __shared__ union {
        unsigned short xb[NROWS * RS];     // 35072 B: x2 bf16 tile
        float band[TH][9][9][18];          // 46656 B: epilogue staging
    } lds;

    // ---- XCD-aware tile swizzle: 576 blocks round-robin XCDs by linear id;
    // remap so each XCD owns 72 consecutive tiles = contiguous (b, ty) slab.
    const int lin = blockIdx.x;
    const int sw  = (lin & 7) * 72 + (lin >> 3);
    const int b   = sw / 144;              // 144 tiles per batch image
    const int t2  = sw - b * 144;
    const int ty  = t2 / 12;
    const int tx  = t2 - ty * 12;

    const int tid  = threadIdx.x;
    const int wv   = tid >> 6;        // wave 0..7 -> h row
    const int lane = tid & 63;
    const int col  = lane & 15;       // MFMA m/n 16-index
    const int q    = lane >> 4;       // MFMA k-quad
    const int w0   = tx * TW;
    const int h0   = ty * TH;
    const int h    = h0 + wv;

    f32x4 acc[9][2];
#pragma unroll
    for (int di = 0; di < 9; ++di) {
        acc[di][0] = (f32x4)0.0f;
        acc[di][1] = (f32x4)0.0f;
    }

    // ---- hoisted per-task state: 1536 tasks/chunk, 3/thread.
    // Remap: seg = t%6 (fastest, 6x float4 = 96 B contiguous per row for
    // coalescing), cp = (t/6)&15, row = t/96 (wave-uniform-ish).
    // LDS write bank = (4*row + 16*(seg&1) + 4p + cp) % 32: cp spans ~11
    // consecutive values within a wave -> ~3-way conflicts (was 8-way).
    unsigned o2k[3];
    int      lofk[3];
    bool     okk[3];
#pragma unroll
    for (int k = 0; k < 3; ++k) {
        const int t   = tid + k * 512;
        const int seg = t % 6;
        const int u   = t / 6;
        const int cp  = u & 15;
        const int row = u >> 4;
        const int gh  = h0 - 4 + row;
        const int gw  = w0 - 4 + seg * 4;
        okk[k] = (gh >= 0) & (gh < HH) & (gw >= 0) & (gw <= WW - 4);
        const int ghc = gh < 0 ? 0 : (gh > HH - 1 ? HH - 1 : gh);
        const int gwc = gw < 0 ? 0 : gw;
        o2k[k]  = (unsigned)(((b * NC + cp * 2) * HH + ghc) * WW + gwc);
        lofk[k] = XBI(row, cp >> 2, seg * 4) + (cp & 3) * 2;
    }
    unsigned o1 = (unsigned)(((b * NC + q * 8) * HH + h) * WW + w0 + col);

    // Prefetch registers: 3 tasks x 2 float4 (x2), 8 floats (x1).
    float pf[24];
    float pa[8];

#define STAGE_LOAD()                                                     \
    {                                                                    \
        _Pragma("unroll")                                                \
        for (int k = 0; k < 3; ++k) {                                    \
            _Pragma("unroll")                                            \
            for (int e = 0; e < 2; ++e) {                                \
                float4 ld = make_float4(0.f, 0.f, 0.f, 0.f);             \
                if (okk[k]) ld = *(const float4*)&x2[o2k[k] + e * CHW];  \
                *(float4*)&pf[(k * 2 + e) * 4] = ld;                     \
            }                                                            \
            o2k[k] += KSTRIDE;                                           \
        }                                                                \
    }

#define X1_LOAD()                                                        \
    {                                                                    \
        _Pragma("unroll")                                                \
        for (int j = 0; j < 8; ++j) pa[j] = x1[o1 + j * CHW];            \
        o1 += KSTRIDE;                                                   \
    }

    STAGE_LOAD();
    X1_LOAD();

    const int rbase = XBI(wv, q, col);   // b1 = +16 n-units = +128 ushorts

    for (int ci = 0; ci < 8; ++ci) {
        // ---- convert + store prefetched x2 regs to LDS (vmcnt wait lands here)
#pragma unroll
        for (int k = 0; k < 3; ++k) {
#pragma unroll
            for (int p = 0; p < 4; ++p) {
                ushort2 v;
                v.x = f2bf(pf[(k * 2 + 0) * 4 + p]);
                v.y = f2bf(pf[(k * 2 + 1) * 4 + p]);
                *(ushort2*)&lds.xb[lofk[k] + p * 8] = v;
            }
        }
        // ---- issue NEXT chunk's x2 loads before the barrier: pf regs are
        // free after the convert, and the loads fly during barrier + MFMA.
        if (ci < 7) STAGE_LOAD();
        __syncthreads();

        // ---- pack this chunk's A-frag, then reissue x1 prefetch
        bf16x8 a;
#pragma unroll
        for (int j = 0; j < 8; ++j) a[j] = (short)f2bf(pa[j]);
        if (ci < 7) X1_LOAD();

        // ---- 9 displacements x 2 n-halves
#pragma unroll
        for (int di = 0; di < 9; ++di) {
            bf16x8 b0 = *(const bf16x8*)&lds.xb[rbase + di * RS];
            bf16x8 b1 = *(const bf16x8*)&lds.xb[rbase + di * RS + 128];
            acc[di][0] = __builtin_amdgcn_mfma_f32_16x16x32_bf16(a, b0, acc[di][0], 0, 0, 0);
            acc[di][1] = __builtin_amdgcn_mfma_f32_16x16x32_bf16(a, b1, acc[di][1], 0, 0, 0);
        }
        __syncthreads();   // frag reads done before next store (or band) overwrites
    }

    // ---- band extraction: P[m, m+dj] -> band[wv][di][dj][m]
    // D layout: col = lane&15 (=n), row m = q*4 + reg.
#pragma unroll
    for (int di = 0; di < 9; ++di)
#pragma unroll
        for (int half = 0; half < 2; ++half)
#pragma unroll
            for (int r = 0; r < 4; ++r) {
                int m  = q * 4 + r;
                int dj = half * 16 + col - m;
                if (dj >= 0 && dj < 9)
                    lds.band[wv][di][dj][m] = acc[di][half][r];
            }
    __syncthreads();

    // ---- coalesced write-out: 81 channels x 16 w per (b, h)
    const float scale = 1.0f / 256.0f;
#pragma unroll
    for (int it = 0; it < 21; ++it) {
        int combo = it * 4 + q;           // (di*9+dj)
        if (combo < 81) {
            float v = lds.band[wv][combo / 9][combo % 9][col];
            out[((size_t)((b * 81 + combo) * HH + h)) * WW + w0 + col] = v * scale;
        }
    }
}

extern "C" void kernel_launch(void* const* d_in, const int* in_sizes, int n_in,
                              void* d_out, int out_size, void* d_ws, size_t ws_size,
                              hipStream_t stream) {
    const float* x1 = (const float*)d_in[0];
    const float* x2 = (const float*)d_in[1];
    float* out = (float*)d_out;

    dim3 grid(576);   // 1-D so the XCD swizzle controls tile placement
    corr_mfma<<<grid, 512, 0, stream>>>(x1, x2, out);
}

// Round 2
// 215.246 us; speedup vs baseline: 1.1326x; 1.0261x over previous
//
#include <hip/hip_runtime.h>
#include <stddef.h>

// Correlation cost volume via bf16 MFMA band-matmul.
// out[b, di*9+dj, h, w] = (1/256) * sum_c x1[b,c,h,w] * x2[b,c,h+di-4,w+dj-4]
// B=4, C=256, H=96, W=192.
//
// R4 -> R5: R4 was residency-bound: acc[9][2] = 72 AGPRs + 64 arch VGPRs
// ~= 136 regs in the unified gfx950 file -> 3 waves/SIMD -> only ONE 8-wave
// block per CU (Occupancy 31%). The __syncthreads() vmcnt(0) drain then
// exposes full L2/L3 latency every chunk with no co-resident block to hide
// it (HBM 14%, VALU 13%, MFMA 4% - everything idle). Fixes:
//  1) Split the 18 (di,half) MFMA units across wave pairs: TH=4, 8 waves,
//     wave (r=wv&3, dig=wv>>2) owns 9 units -> acc[9] = 36 AGPRs. Total
//     regs ~110 -> 4 waves/SIMD -> 2 blocks/CU; barrier drains now overlap
//     with the other block's compute (m114 mechanism).
//  2) Next-chunk loads issued AFTER the first barrier (during MFMA phase),
//     so the chunk-end vmcnt(0) drain is covered by compute.
//  3) LDS tile 12 rows (26.3 KB); grid 1152 with 144-consecutive-tile XCD
//     swizzle (keeps the R4 win: FETCH 333->89 MB, inputs L2/L3-resident).

#define NB 4
#define NC 256
#define HH 96
#define WW 192
#define TW 16
#define TH 4
#define KC 32
#define NROWS 12   // TH + 8 halo rows
#define CHW (HH * WW)         // 18432 floats per channel plane
#define KSTRIDE (KC * CHW)    // chunk-to-chunk float offset
#define NTASK 1152            // 12 rows x 6 segs x 16 ch-pairs per chunk

// Flat LDS bf16 layout for x2 tile: [row][kg=k/8][n][k%8] (k-innermost 8 ->
// one bf16x8 B-frag = 1 ds_read_b128). KS=264, RS=1096 stagger bank groups.
#define KS 264
#define RS 1096
#define XBI(row, kg, n) ((row) * RS + (kg) * KS + (n) * 8)

typedef __attribute__((ext_vector_type(8))) short bf16x8;
typedef __attribute__((ext_vector_type(4))) float f32x4;

__device__ __forceinline__ unsigned short f2bf(float f) {
    union { float f; unsigned u; } c; c.f = f;
    unsigned r = c.u + 0x7FFFu + ((c.u >> 16) & 1u);   // round-to-nearest-even
    return (unsigned short)(r >> 16);
}

__global__ __launch_bounds__(512, 4) void corr_mfma(
    const float* __restrict__ x1, const float* __restrict__ x2,
    float* __restrict__ out)
{
    __shared__ union {
        unsigned short xb[NROWS * RS];     // 26304 B: x2 bf16 tile
        float band[TH][9][9][18];          // 23328 B: epilogue staging
    } lds;

    // ---- XCD-aware tile swizzle: 1152 blocks round-robin XCDs by linear id;
    // remap so each XCD owns 144 consecutive tiles = contiguous (b, ty) slab.
    const int lin = blockIdx.x;
    const int sw  = (lin & 7) * 144 + (lin >> 3);
    const int b   = sw / 288;              // 288 tiles per batch image
    const int t2  = sw - b * 288;
    const int ty  = t2 / 12;
    const int tx  = t2 - ty * 12;

    const int tid  = threadIdx.x;
    const int wv   = tid >> 6;        // 8 waves
    const int lane = tid & 63;
    const int col  = lane & 15;       // MFMA m/n 16-index
    const int q    = lane >> 4;       // MFMA k-quad
    const int r    = wv & 3;          // output row within tile
    const int dig  = wv >> 2;         // unit group: 0 -> units 0..8, 1 -> 9..17
    const int w0   = tx * TW;
    const int h0   = ty * TH;
    const int h    = h0 + r;

    // wave owns 9 of 18 units; unit u = di*2 + half
    f32x4 acc[9];
#pragma unroll
    for (int s = 0; s < 9; ++s) acc[s] = (f32x4)0.0f;

    // ---- hoisted per-task state: 1152 tasks/chunk, <=3/thread.
    // task t: seg = t%6 (6x float4 = 96 B contiguous for coalescing),
    // cp = (t/6)&15 (channel pair), row = (t/6)>>4.
    unsigned o2k[3];
    int      lofk[3];
    bool     okk[3];
    bool     act[3];
#pragma unroll
    for (int k = 0; k < 3; ++k) {
        const int t   = tid + k * 512;
        act[k] = (t < NTASK);              // k<2 always active; k==2: tid<128
        const int seg = t % 6;
        const int u   = t / 6;
        const int cp  = u & 15;
        const int row = u >> 4;
        const int gh  = h0 - 4 + row;
        const int gw  = w0 - 4 + seg * 4;
        okk[k] = act[k] & (gh >= 0) & (gh < HH) & (gw >= 0) & (gw <= WW - 4);
        const int ghc = gh < 0 ? 0 : (gh > HH - 1 ? HH - 1 : gh);
        const int gwc = gw < 0 ? 0 : gw;
        const int rwc = row > NROWS - 1 ? NROWS - 1 : row;
        o2k[k]  = (unsigned)(((b * NC + cp * 2) * HH + ghc) * WW + gwc);
        lofk[k] = XBI(rwc, cp >> 2, seg * 4) + (cp & 3) * 2;
    }
    unsigned o1 = (unsigned)(((b * NC + q * 8) * HH + h) * WW + w0 + col);

    // Prefetch registers: 3 tasks x 2 float4 (x2), 8 floats (x1).
    float pf[24];
    float pa[8];

#define STAGE_LOAD()                                                     \
    {                                                                    \
        _Pragma("unroll")                                                \
        for (int k = 0; k < 3; ++k) {                                    \
            _Pragma("unroll")                                            \
            for (int e = 0; e < 2; ++e) {                                \
                float4 ld = make_float4(0.f, 0.f, 0.f, 0.f);             \
                if (okk[k]) ld = *(const float4*)&x2[o2k[k] + e * CHW];  \
                *(float4*)&pf[(k * 2 + e) * 4] = ld;                     \
            }                                                            \
            o2k[k] += KSTRIDE;                                           \
        }                                                                \
    }

#define X1_LOAD()                                                        \
    {                                                                    \
        _Pragma("unroll")                                                \
        for (int j = 0; j < 8; ++j) pa[j] = x1[o1 + j * CHW];            \
        o1 += KSTRIDE;                                                   \
    }

    STAGE_LOAD();
    X1_LOAD();

    const int rbase = XBI(r, q, col);   // +di*RS rows, +128 ushorts for n-half 1

    for (int ci = 0; ci < 8; ++ci) {
        // ---- convert + store prefetched x2 regs to LDS (vmcnt wait lands here)
#pragma unroll
        for (int k = 0; k < 3; ++k) {
            if (act[k]) {
#pragma unroll
                for (int p = 0; p < 4; ++p) {
                    ushort2 v;
                    v.x = f2bf(pf[(k * 2 + 0) * 4 + p]);
                    v.y = f2bf(pf[(k * 2 + 1) * 4 + p]);
                    *(ushort2*)&lds.xb[lofk[k] + p * 8] = v;
                }
            }
        }
        __syncthreads();

        // ---- pack this chunk's A-frag (waits on pa), then issue NEXT chunk's
        // loads so their vmcnt(0) drain at the chunk-end barrier is covered by
        // the MFMA phase below.
        bf16x8 a;
#pragma unroll
        for (int j = 0; j < 8; ++j) a[j] = (short)f2bf(pa[j]);
        if (ci < 7) {
            STAGE_LOAD();
            X1_LOAD();
        }

        // ---- this wave's 9 (di, half) units
#pragma unroll
        for (int s = 0; s < 9; ++s) {
            const int u    = dig * 9 + s;
            const int di   = u >> 1;
            const int half = u & 1;
            bf16x8 bb = *(const bf16x8*)&lds.xb[rbase + di * RS + half * 128];
            acc[s] = __builtin_amdgcn_mfma_f32_16x16x32_bf16(a, bb, acc[s], 0, 0, 0);
        }
        __syncthreads();   // frag reads done before next store (or band) overwrites
    }

    // ---- band extraction: P[m, m+dj] -> band[r][di][dj][m]
    // D layout: col = lane&15 (=n), row m = q*4 + reg.
#pragma unroll
    for (int s = 0; s < 9; ++s) {
        const int u  = dig * 9 + s;
        const int di = u >> 1;
        const int uh = u & 1;
#pragma unroll
        for (int rg = 0; rg < 4; ++rg) {
            int m  = q * 4 + rg;
            int dj = uh * 16 + col - m;
            if (dj >= 0 && dj < 9)
                lds.band[r][di][dj][m] = acc[s][rg];
        }
    }
    __syncthreads();

    // ---- coalesced write-out: 81 channels x 4 rows x 16 w per block
    const float scale = 1.0f / 256.0f;
#pragma unroll
    for (int it = 0; it < 11; ++it) {
        int gi = it * 32 + (tid >> 4);    // gi = combo*4 + row, 324 total
        if (gi < 324) {
            int combo = gi >> 2;
            int row   = gi & 3;
            float v = lds.band[row][combo / 9][combo % 9][tid & 15];
            out[((size_t)((b * 81 + combo) * HH + h0 + row)) * WW + w0 + (tid & 15)] = v * scale;
        }
    }
}

extern "C" void kernel_launch(void* const* d_in, const int* in_sizes, int n_in,
                              void* d_out, int out_size, void* d_ws, size_t ws_size,
                              hipStream_t stream) {
    const float* x1 = (const float*)d_in[0];
    const float* x2 = (const float*)d_in[1];
    float* out = (float*)d_out;

    dim3 grid(1152);   // 1-D so the XCD swizzle controls tile placement
    corr_mfma<<<grid, 512, 0, stream>>>(x1, x2, out);
}